// Round 1
// baseline (140.068 us; speedup 1.0000x reference)
//
#include <hip/hip_runtime.h>

constexpr int EMB = 256;
constexpr float FEPS = 1e-6f;

// fast tanh via native exp2-based __expf; clamp so exp doesn't overflow to inf
__device__ __forceinline__ float ftanh(float x) {
    x = fminf(15.f, fmaxf(-15.f, x));
    float t = __expf(2.f * x);
    return (t - 1.f) * __builtin_amdgcn_rcpf(t + 1.f);
}

// one per-dim squared-distance term
__device__ __forceinline__ float dist2_term(float wabs, float scale, float c, float bm) {
    float w   = ftanh(wabs * scale);
    float ct  = ftanh(c);
    float bt  = ftanh(bm);
    float cd  = fabsf(bt - ct);
    float wp1 = w + 1.f;
    float inv = __builtin_amdgcn_rcpf(wp1);
    float kappa = 0.5f * w * (wp1 - inv);
    float dist = (cd <= 0.5f * w) ? (cd * inv) : fmaf(cd, wp1, -kappa);
    return dist * dist;
}

__global__ __launch_bounds__(256) void boxe_kernel(
    const float* __restrict__ head, const int* __restrict__ rid,
    const float* __restrict__ tail, const float* __restrict__ rel,
    float* __restrict__ out, int batch)
{
    const int gwave = (int)(((size_t)blockIdx.x * blockDim.x + threadIdx.x) >> 6);
    const int lane  = threadIdx.x & 63;
    if (gwave >= batch) return;
    const int b = gwave;

    const long r = rid[b];
    const float* __restrict__ rrow = rel  + r * (long)(4 * EMB + 2);
    const float* __restrict__ hrow = head + (long)b * (2 * EMB);
    const float* __restrict__ trow = tail + (long)b * (2 * EMB);
    const int d0 = lane * 4;

    // vectorized, fully-coalesced loads: lane i covers dims [4i,4i+4)
    float hp[4], hb[4], tp[4], tb[4], c0[4], c1[4], w0[4], w1[4];
    *(float4*)hp = *(const float4*)(hrow + d0);
    *(float4*)hb = *(const float4*)(hrow + EMB + d0);
    *(float4*)tp = *(const float4*)(trow + d0);
    *(float4*)tb = *(const float4*)(trow + EMB + d0);
    *(float4*)c0 = *(const float4*)(rrow + d0);
    *(float4*)c1 = *(const float4*)(rrow + EMB + d0);
    *(float4*)w0 = *(const float4*)(rrow + 2 * EMB + d0);
    *(float4*)w1 = *(const float4*)(rrow + 3 * EMB + d0);
    const float bs0 = rrow[4 * EMB + 0];
    const float bs1 = rrow[4 * EMB + 1];

    // |width| and log-sum for geometric mean (both heads in one pass)
    float wa0[4], wa1[4];
    float ls0 = 0.f, ls1 = 0.f;
#pragma unroll
    for (int j = 0; j < 4; ++j) {
        wa0[j] = fabsf(w0[j]);
        wa1[j] = fabsf(w1[j]);
        ls0 += __logf(fmaxf(wa0[j], FEPS));
        ls1 += __logf(fmaxf(wa1[j], FEPS));
    }
#pragma unroll
    for (int off = 32; off >= 1; off >>= 1) {
        ls0 += __shfl_xor(ls0, off, 64);
        ls1 += __shfl_xor(ls1, off, 64);
    }
    const float g0 = __expf(ls0 * (1.f / (2 * EMB / 2)));  // mean over 256 dims
    const float g1 = __expf(ls1 * (1.f / 256.f));
    const float e0 = (bs0 > 0.f) ? bs0 : (__expf(bs0) - 1.f);  // elu
    const float e1 = (bs1 > 0.f) ? bs1 : (__expf(bs1) - 1.f);
    const float s0 = (1.f + e0) / fmaxf(g0, FEPS);
    const float s1 = (1.f + e1) / fmaxf(g1, FEPS);

    // per-dim distance terms; h0: head_pos + tail_bump, h1: tail_pos + head_bump
    float acc0 = 0.f, acc1 = 0.f;
#pragma unroll
    for (int j = 0; j < 4; ++j) {
        acc0 += dist2_term(wa0[j], s0, c0[j], hp[j] + tb[j]);
        acc1 += dist2_term(wa1[j], s1, c1[j], tp[j] + hb[j]);
    }
#pragma unroll
    for (int off = 32; off >= 1; off >>= 1) {
        acc0 += __shfl_xor(acc0, off, 64);
        acc1 += __shfl_xor(acc1, off, 64);
    }
    if (lane == 0) out[b] = -(sqrtf(acc0) + sqrtf(acc1));
}

extern "C" void kernel_launch(void* const* d_in, const int* in_sizes, int n_in,
                              void* d_out, int out_size, void* d_ws, size_t ws_size,
                              hipStream_t stream) {
    const float* head = (const float*)d_in[0];
    const int*   rid  = (const int*)d_in[1];
    const float* tail = (const float*)d_in[2];
    const float* rel  = (const float*)d_in[3];
    float* out = (float*)d_out;

    const int batch = out_size;            // 131072 scores
    const int wavesPerBlock = 256 / 64;    // 4
    const int blocks = (batch + wavesPerBlock - 1) / wavesPerBlock;
    boxe_kernel<<<blocks, 256, 0, stream>>>(head, rid, tail, rel, out, batch);
}